// Round 1
// baseline (1724.892 us; speedup 1.0000x reference)
//
#include <hip/hip_runtime.h>

// RSSM scan: B=2048, L=64. Per step (batch-row independent!):
//   gates = [s,a,h] @ W^T; r,z sigmoid; n = tanh(inn + r*hn); h' = (1-z)n + z h
//   prior: relu(h'@pW1^T+pb1)@pW2^T+pb2 ; post: relu([obs,h']@qW1^T+qb1)@qW2^T+qb2
//   s' = mu_q + std_q * eps ; out = [mu_p,std_p,mu_q,std_q,s',h'] (350 f32 per (b,l))
// Design: 128 blocks x 512 thr; block owns 16 batch rows for all 64 steps.
// bf16 MFMA 16x16x32; weights pre-packed into B-fragment order by pack_w.

typedef unsigned short u16;
typedef unsigned int u32;
typedef __attribute__((ext_vector_type(8))) short short8;
typedef __attribute__((ext_vector_type(4))) float f32x4;

#define LL 64
#define OBS_ 200
#define ACT_ 6
#define STO 30
#define OUTC 350

// packed-weight unit offsets (1 unit = 1KB = 64 lanes x 16B)
// WG: 52 nt x 9 ks   | N-layout [r 208 | z 208 | inn 208 | hn 208], K=288 ([s30,a6,z28 | h200,z24])
// PW1: 13 x 7 (K=224,N=208)  QW1: 13 x 14 (K=448: [obs224|h224], N=208)
// PW2/QW2: 4 x 7 (K=224, N=[mu32|pre32])
#define U_WG   0
#define U_PW1  468
#define U_QW1  559
#define U_PW2  741
#define U_QW2  769
#define U_TOT  797

__device__ __forceinline__ u16 f2b(float f){
  u32 u = __float_as_uint(f);
  u = (u + 0x7fffu + ((u >> 16) & 1u)) >> 16;   // RNE
  return (u16)u;
}
__device__ __forceinline__ float b2f(u16 h){ return __uint_as_float(((u32)h) << 16); }

// LDS XOR swizzle: byte ^= (row&7)<<4 ; all strides multiples of 128B so the
// XOR stays inside the row (G4 pattern; <=2-way conflicts on ds_read_b128).
__device__ __forceinline__ short8 ldA(const u16* buf, int strideB, int r, int colStart){
  return *(const short8*)((const char*)buf + r*strideB + ((colStart*2) ^ ((r & 7) << 4)));
}
__device__ __forceinline__ void st2(u16* buf, int strideB, int r, int c, u16 v){
  *(u16*)((char*)buf + r*strideB + ((c*2) ^ ((r & 7) << 4))) = v;
}
__device__ __forceinline__ u16 ld2(const u16* buf, int strideB, int r, int c){
  return *(const u16*)((const char*)buf + r*strideB + ((c*2) ^ ((r & 7) << 4)));
}
__device__ __forceinline__ short8 ldB(const char* wsb, int unit, int lane){
  return *(const short8*)(wsb + (((size_t)unit) << 10) + ((size_t)lane << 4));
}
__device__ __forceinline__ f32x4 mfma(short8 a, short8 b, f32x4 c){
  return __builtin_amdgcn_mfma_f32_16x16x32_bf16(a, b, c, 0, 0, 0);
}
__device__ __forceinline__ float sigm(float x){ return 1.f / (1.f + __expf(-x)); }
__device__ __forceinline__ float tanhf_(float x){
  x = fminf(fmaxf(x, -15.f), 15.f);
  float e = __expf(-2.f * x);
  return (1.f - e) / (1.f + e);
}
__device__ __forceinline__ float softplus_(float x){
  return (x > 20.f) ? x : log1pf(__expf(x));
}

// ---------------- weight packing: f32 torch-layout -> bf16 B-fragment order --------
// element (unit u, lane, j): value = W^T[k][n] with k = ks*32+(lane>>4)*8+j, n = nt*16+(lane&15)
__global__ __launch_bounds__(512) void pack_w(
    const float* W_ih, const float* W_hh, const float* pW1f, const float* qW1f,
    const float* pW2f, const float* qW2f, u16* wsu)
{
  int u = blockIdx.x;
  int t = threadIdx.x;
  int lane = t >> 3, j = t & 7;
  int nl = lane & 15, kg = lane >> 4;
  float v = 0.f;
  if (u < U_PW1) {                       // WG
    int nt = u / 9, ks = u % 9;
    int k = ks*32 + kg*8 + j;            // K=288: [0,36) x=[s,a]; [64,264) h; else 0
    int c = nt*16 + nl;                  // 832 cols: r z inn hn regions (208 each)
    int grow, part, coff;                // part: 0=both,1=x-only,2=h-only
    if (c < 208)      { grow = c;            part = 0; coff = c; }
    else if (c < 416) { grow = 200 + (c-208); part = 0; coff = c-208; }
    else if (c < 624) { grow = 400 + (c-416); part = 1; coff = c-416; }
    else              { grow = 400 + (c-624); part = 2; coff = c-624; }
    if (coff < 200) {
      if (k < 36)                  { if (part != 2) v = W_ih[grow*36 + k]; }
      else if (k >= 64 && k < 264) { if (part != 1) v = W_hh[grow*200 + (k-64)]; }
    }
  } else if (u < U_QW1) {                // PW1
    int uu = u - U_PW1; int nt = uu / 7, ks = uu % 7;
    int k = ks*32 + kg*8 + j; int n = nt*16 + nl;
    if (n < 200 && k < 200) v = pW1f[n*200 + k];
  } else if (u < U_PW2) {                // QW1
    int uu = u - U_QW1; int nt = uu / 14, ks = uu % 14;
    int k = ks*32 + kg*8 + j; int n = nt*16 + nl;
    if (n < 200) {
      if (k < 200) v = qW1f[n*400 + k];
      else if (k >= 224 && k < 424) v = qW1f[n*400 + 200 + (k-224)];
    }
  } else {                               // PW2 / QW2
    bool isQ = (u >= U_QW2);
    int uu = u - (isQ ? U_QW2 : U_PW2); int nt = uu / 7, ks = uu % 7;
    int k = ks*32 + kg*8 + j; int c = nt*16 + nl;
    int row = (c < 32) ? c : 30 + (c - 32);
    bool ok = (c < 32) ? (c < 30) : ((c - 32) < 30);
    const float* W = isQ ? qW2f : pW2f;
    if (ok && k < 200) v = W[row*200 + k];
  }
  wsu[((size_t)u << 9) + lane*8 + j] = f2b(v);
}

// ---------------- main persistent scan kernel ---------------------------------
__global__ __launch_bounds__(512) void rssm_main(
    const float* __restrict__ obs, const float* __restrict__ act,
    const float* __restrict__ noise,
    const float* __restrict__ b_ih, const float* __restrict__ b_hh,
    const float* __restrict__ pb1, const float* __restrict__ pb2,
    const float* __restrict__ qb1, const float* __restrict__ qb2,
    const char* __restrict__ wsb, float* __restrict__ out)
{
  const int tid  = threadIdx.x;
  const int w    = tid >> 6;      // wave 0..7
  const int lane = tid & 63;
  const int nl   = lane & 15;     // A-row / B-col / D-col
  const int kg   = lane >> 4;     // k-group; D-rows kg*4+i
  const int m0   = blockIdx.x * 16;

  // sx  [16][64]  : s(0..29) a(30..35) zeros(36..63)          stride 128B
  // sq  [16][704] : obs(0..199) pad | hA@224 pad | hB@448 pad  stride 1408B
  // spp/sqq [16][256]: p1/q1 (0..199) + zero pad               stride 512B
  __shared__ __align__(16) u16 sx [16*64];
  __shared__ __align__(16) u16 sq [16*704];
  __shared__ __align__(16) u16 spp[16*256];
  __shared__ __align__(16) u16 sqq[16*256];
  __shared__ float sr[16*64];     // qp epilogue: mu(0..29), std(32..61)

  for (int i = tid; i < 16*64;  i += 512) sx[i]  = 0;
  for (int i = tid; i < 16*704; i += 512) sq[i]  = 0;
  for (int i = tid; i < 16*256; i += 512) { spp[i] = 0; sqq[i] = 0; }
  __syncthreads();
  {  // prologue: obs[.,0,.], act[.,0,.]  (s0=h0=0 already)
    if (tid < 96) {
      int m = tid / 6, jj = tid % 6;
      st2(sx, 128, m, 30 + jj, f2b(act[(size_t)(m0+m)*LL*ACT_ + jj]));
    }
    int m = tid >> 5, c0 = tid & 31;
    const float* op = obs + (size_t)(m0+m)*LL*OBS_;
    for (int c = c0; c < 200; c += 32) st2(sq, 1408, m, c, f2b(op[c]));
  }
  __syncthreads();

  for (int l = 0; l < LL; ++l) {
    const int holdC = (l & 1) ? 448 : 224;   // h from step l-1
    const int hnewC = (l & 1) ? 224 : 448;   // h written this step
    const size_t outRowBase = (size_t)l*OUTC;

    // ---- P1: fused gate GEMM (r,z,inn,hn same wave => gate math in-register) ----
    for (int qi = 0; qi < 2; ++qi) {
      int tq = w + qi*8;
      if (tq < 13) {
        f32x4 aR{0,0,0,0}, aZ{0,0,0,0}, aI{0,0,0,0}, aH{0,0,0,0};
#pragma unroll
        for (int ks = 0; ks < 9; ++ks) {
          short8 af = (ks < 2) ? ldA(sx, 128, nl, ks*32 + kg*8)
                               : ldA(sq, 1408, nl, holdC + (ks-2)*32 + kg*8);
          short8 bR = ldB(wsb, U_WG + (     tq)*9 + ks, lane);
          short8 bZ = ldB(wsb, U_WG + (13 + tq)*9 + ks, lane);
          aR = mfma(af, bR, aR);
          aZ = mfma(af, bZ, aZ);
          if (ks < 2)  { short8 bI = ldB(wsb, U_WG + (26 + tq)*9 + ks, lane); aI = mfma(af, bI, aI); }
          if (ks >= 2) { short8 bH = ldB(wsb, U_WG + (39 + tq)*9 + ks, lane); aH = mfma(af, bH, aH); }
        }
        int cj = tq*16 + nl;
        if (cj < 200) {
          float bR = b_ih[cj]       + b_hh[cj];
          float bZ = b_ih[200 + cj] + b_hh[200 + cj];
          float bI = b_ih[400 + cj];
          float bH = b_hh[400 + cj];
#pragma unroll
          for (int i = 0; i < 4; ++i) {
            int m = kg*4 + i;
            float r = sigm(aR[i] + bR);
            float z = sigm(aZ[i] + bZ);
            float n = tanhf_(aI[i] + bI + r*(aH[i] + bH));
            float hold = b2f(ld2(sq, 1408, m, holdC + cj));
            float hnew = (1.f - z)*n + z*hold;
            st2(sq, 1408, m, hnewC + cj, f2b(hnew));
            out[(size_t)(m0+m)*LL*OUTC + outRowBase + 150 + cj] = hnew;
          }
        }
      }
    }
    __syncthreads();

    // ---- P2: post1 ([obs,h']@qW1^T) and prior1 (h'@pW1^T), relu+bias in-reg ----
    for (int qi = 0; qi < 2; ++qi) {
      int tq = w + qi*8;
      if (tq < 13) {
        int n = tq*16 + nl;
        f32x4 aq{0,0,0,0};
#pragma unroll
        for (int ks = 0; ks < 14; ++ks) {
          short8 af = (ks < 7) ? ldA(sq, 1408, nl, ks*32 + kg*8)
                               : ldA(sq, 1408, nl, hnewC + (ks-7)*32 + kg*8);
          aq = mfma(af, ldB(wsb, U_QW1 + tq*14 + ks, lane), aq);
        }
        if (n < 200) {
          float bias = qb1[n];
#pragma unroll
          for (int i = 0; i < 4; ++i) {
            float v = aq[i] + bias;
            st2(sqq, 512, kg*4 + i, n, f2b(v > 0.f ? v : 0.f));
          }
        }
        f32x4 ap{0,0,0,0};
#pragma unroll
        for (int ks = 0; ks < 7; ++ks) {
          short8 af = ldA(sq, 1408, nl, hnewC + ks*32 + kg*8);
          ap = mfma(af, ldB(wsb, U_PW1 + tq*7 + ks, lane), ap);
        }
        if (n < 200) {
          float bias = pb1[n];
#pragma unroll
          for (int i = 0; i < 4; ++i) {
            float v = ap[i] + bias;
            st2(spp, 512, kg*4 + i, n, f2b(v > 0.f ? v : 0.f));
          }
        }
      }
    }
    __syncthreads();

    // ---- P3: head GEMMs. waves 0..3: prior2 ; waves 4..7: post2 ----
    {
      int nt = w & 3;
      bool isQ = (w >= 4);
      const u16* src = isQ ? sqq : spp;
      f32x4 acc{0,0,0,0};
#pragma unroll
      for (int ks = 0; ks < 7; ++ks) {
        short8 af = ldA(src, 512, nl, ks*32 + kg*8);
        acc = mfma(af, ldB(wsb, (isQ ? U_QW2 : U_PW2) + nt*7 + ks, lane), acc);
      }
      int c = nt*16 + nl;
      const float* b2 = isQ ? qb2 : pb2;
      if (c < 32) {
        if (c < 30) {
          float bias = b2[c];
#pragma unroll
          for (int i = 0; i < 4; ++i) {
            int m = kg*4 + i;
            float mu = acc[i] + bias;
            out[(size_t)(m0+m)*LL*OUTC + outRowBase + (isQ ? 60 : 0) + c] = mu;
            if (isQ) sr[m*64 + c] = mu;
          }
        }
      } else {
        int rp = c - 32;
        if (rp < 30) {
          float bias = b2[30 + rp];
#pragma unroll
          for (int i = 0; i < 4; ++i) {
            int m = kg*4 + i;
            float sp = softplus_(acc[i] + bias) + 1e-5f;
            float sd = sp > 1e-4f ? sp : 1e-4f;
            out[(size_t)(m0+m)*LL*OUTC + outRowBase + (isQ ? 90 : 30) + rp] = sd;
            if (isQ) sr[m*64 + 32 + rp] = sd;
          }
        }
      }
    }
    __syncthreads();

    // ---- P4: reparameterize s' ; prefetch obs/act for l+1 ----
    if (tid < 480) {
      int m = tid / 30, jj = tid % 30;
      float mu = sr[m*64 + jj];
      float sd = sr[m*64 + 32 + jj];
      float eps = noise[(size_t)(m0+m)*LL*STO + (size_t)l*STO + jj];
      float s = mu + sd*eps;
      out[(size_t)(m0+m)*LL*OUTC + outRowBase + 120 + jj] = s;
      st2(sx, 128, m, jj, f2b(s));
    }
    if (l + 1 < LL) {
      if (tid < 96) {
        int m = tid / 6, jj = tid % 6;
        st2(sx, 128, m, 30 + jj, f2b(act[(size_t)(m0+m)*LL*ACT_ + (size_t)(l+1)*ACT_ + jj]));
      }
      int m = tid >> 5, c0 = tid & 31;
      const float* op = obs + (size_t)(m0+m)*LL*OBS_ + (size_t)(l+1)*OBS_;
      for (int c = c0; c < 200; c += 32) st2(sq, 1408, m, c, f2b(op[c]));
    }
    __syncthreads();
  }
}

extern "C" void kernel_launch(void* const* d_in, const int* in_sizes, int n_in,
                              void* d_out, int out_size, void* d_ws, size_t ws_size,
                              hipStream_t stream) {
  const float* obs   = (const float*)d_in[0];
  const float* act   = (const float*)d_in[1];
  const float* noise = (const float*)d_in[2];
  const float* W_ih  = (const float*)d_in[3];
  const float* b_ih  = (const float*)d_in[4];
  const float* W_hh  = (const float*)d_in[5];
  const float* b_hh  = (const float*)d_in[6];
  const float* pW1   = (const float*)d_in[7];
  const float* pb1   = (const float*)d_in[8];
  const float* pW2   = (const float*)d_in[9];
  const float* pb2   = (const float*)d_in[10];
  const float* qW1   = (const float*)d_in[11];
  const float* qb1   = (const float*)d_in[12];
  const float* qW2   = (const float*)d_in[13];
  const float* qb2   = (const float*)d_in[14];
  float* out = (float*)d_out;

  pack_w<<<U_TOT, 512, 0, stream>>>(W_ih, W_hh, pW1, qW1, pW2, qW2, (u16*)d_ws);
  rssm_main<<<128, 512, 0, stream>>>(obs, act, noise, b_ih, b_hh,
                                     pb1, pb2, qb1, qb2,
                                     (const char*)d_ws, out);
}